// Round 10
// baseline (594.124 us; speedup 1.0000x reference)
//
#include <hip/hip_runtime.h>
#include <hip/hip_bf16.h>

// Problem constants (from reference setup_inputs)
constexpr int NN   = 50000;   // nodes
constexpr int EE   = 400000;  // edges (before self loops)
constexpr int EP   = 450000;  // edges + self loops
constexpr int D    = 512;     // HEADS*CH
constexpr int D2   = 1024;    // XL||XR fused row stride
constexpr int F0   = 55;      // input feature dim
constexpr int F0P  = 64;      // padded to MFMA K granularity
constexpr int OUTC = 49;      // classifier out dim

typedef __hip_bfloat16 bf16;

using frag_ab  = __attribute__((ext_vector_type(8))) short;   // 8 bf16 (4 VGPRs)
using frag_cd4 = __attribute__((ext_vector_type(4))) float;   // 4 fp32 (16x16 acc)
typedef float v2f __attribute__((ext_vector_type(2)));        // -> v_pk_*_f32

__device__ inline void stf(float* p, float v) { *p = v; }
__device__ inline void stf(bf16* p, float v)  { *p = __float2bfloat16(v); }

// unpack 8 bf16 (packed in a uint4) to 4 float-pairs (VOP3P operands)
__device__ inline void unpack8v(uint4 u, v2f* f) {
    unsigned w[4] = {u.x, u.y, u.z, u.w};
    #pragma unroll
    for (int j = 0; j < 4; ++j) {
        __hip_bfloat162 h = *(__hip_bfloat162*)&w[j];
        float2 t = __bfloat1622float2(h);
        f[j] = v2f{t.x, t.y};
    }
}

// ---------------------------------------------------------------------------
// Round-13 GEMM (kept verbatim — measured best, r3). Deep-pipeline,
// 2-blocks/CU. C[M,*] = A @ Bt^T.
//   BK=32, 3-slot ring (A 16K + B 8K)x3 = 72 KB  -> 2 blocks/CU,
//   __launch_bounds__(512,4) caps VGPR at 128 to guarantee residency.
//   Per K-step/wave: stage(s+2) 3x global_load_lds, 8x ds_read_b128,
//   16x mfma_16x16x32_bf16 (setprio-wrapped), ONE barrier, counted
//   s_waitcnt vmcnt(3). T2 swizzle both-sides (rule #21): 4 chunks/row,
//   chunk ^= (row>>1)&3 (residual 2-way conflict is free, m136).
// ---------------------------------------------------------------------------
template <typename TC, int NS>
__global__ __launch_bounds__(512, 4) void gemm_dp(
    const bf16* __restrict__ A,   // [M,K]
    const bf16* __restrict__ Bt,  // [>=gridx*128 rows, K]
    TC* __restrict__ C,           // [M, Ncs]
    const float* __restrict__ bias,
    int M, int Ncs)
{
    constexpr int K  = NS * 32;
    constexpr int BM = 256, BN = 128, BK = 32;
    __shared__ __align__(16) bf16 As[3][BM * BK];   // 16 KB / slot
    __shared__ __align__(16) bf16 Bs[3][BN * BK];   //  8 KB / slot

    int bx = blockIdx.x, by = blockIdx.y;
    if (gridDim.x == 8) {
        int bid = by * 8 + bx;
        bx = (bid >> 3) & 7;
        by = (bid & 7) + ((bid >> 6) << 3);
    }
    if (by * BM >= M) return;   // uniform across block

    const int tid = threadIdx.x;
    const int w   = tid >> 6;       // wave 0..7
    const int l   = tid & 63;
    const int rowBase = by * BM;
    const int colBase = bx * BN;

    // ---- staging source pointers (inverse-swizzled global chunks) ----
    const bf16* gA[2];
    #pragma unroll
    for (int j = 0; j < 2; ++j) {
        int f = j * 512 + tid;
        int row = f >> 2, c = (f & 3) ^ ((row >> 1) & 3);
        int ar = rowBase + row; if (ar >= M) ar = M - 1;  // clamp, never stored
        gA[j] = A + (size_t)ar * K + c * 8;
    }
    const bf16* gB;
    {
        int f = tid;
        int row = f >> 2, c = (f & 3) ^ ((row >> 1) & 3);
        gB = Bt + (size_t)(colBase + row) * K + c * 8;    // Bt rows padded
    }

    // ---- fragment read offsets (swizzled), element units ----
    const int l15 = l & 15, l4 = l >> 4;    // l4 = k-chunk 0..3
    const int wm = (w >> 1) * 64;   // wave M-block (4 x 64 rows)
    const int wn = (w & 1) * 64;    // wave N-block (2 x 64 cols)
    int aoff[4], boff[4];
    #pragma unroll
    for (int i = 0; i < 4; ++i) {
        int ra = wm + i * 16 + l15;
        int rb = wn + i * 16 + l15;
        aoff[i] = ra * BK + ((l4 ^ ((ra >> 1) & 3)) * 8);
        boff[i] = rb * BK + ((l4 ^ ((rb >> 1) & 3)) * 8);
    }

    frag_cd4 acc[4][4] = {};

    auto stage = [&](int s) {
        int slot = s % 3;
        __builtin_amdgcn_global_load_lds(
            (const __attribute__((address_space(1))) void*)(gA[0] + s * BK),
            (__attribute__((address_space(3))) void*)(&As[slot][(w * 64) * 8]),
            16, 0, 0);
        __builtin_amdgcn_global_load_lds(
            (const __attribute__((address_space(1))) void*)(gA[1] + s * BK),
            (__attribute__((address_space(3))) void*)(&As[slot][(512 + w * 64) * 8]),
            16, 0, 0);
        __builtin_amdgcn_global_load_lds(
            (const __attribute__((address_space(1))) void*)(gB + s * BK),
            (__attribute__((address_space(3))) void*)(&Bs[slot][(w * 64) * 8]),
            16, 0, 0);
    };

    stage(0);
    if (NS > 1) stage(1);

    #pragma unroll
    for (int s = 0; s < NS; ++s) {
        if (s + 1 < NS) asm volatile("s_waitcnt vmcnt(3)" ::: "memory");
        else            asm volatile("s_waitcnt vmcnt(0)" ::: "memory");
        __builtin_amdgcn_s_barrier();
        asm volatile("" ::: "memory");

        if (s + 2 < NS) stage(s + 2);   // overwrites slot(s-1): WAR-safe

        const bf16* Ab = As[s % 3];
        const bf16* Bb = Bs[s % 3];
        frag_ab a[4], b[4];
        #pragma unroll
        for (int i = 0; i < 4; ++i) a[i] = *(const frag_ab*)&Ab[aoff[i]];
        #pragma unroll
        for (int n = 0; n < 4; ++n) b[n] = *(const frag_ab*)&Bb[boff[n]];

        __builtin_amdgcn_s_setprio(1);
        #pragma unroll
        for (int i = 0; i < 4; ++i)
            #pragma unroll
            for (int n = 0; n < 4; ++n)
                acc[i][n] = __builtin_amdgcn_mfma_f32_16x16x32_bf16(
                    a[i], b[n], acc[i][n], 0, 0, 0);
        __builtin_amdgcn_s_setprio(0);
    }

    // ---- epilogue: 16x16 C/D layout col=lane&15, row=(lane>>4)*4+reg ----
    #pragma unroll
    for (int mi = 0; mi < 4; ++mi) {
        #pragma unroll
        for (int r = 0; r < 4; ++r) {
            int row = rowBase + wm + mi * 16 + l4 * 4 + r;
            if (row >= M) continue;
            #pragma unroll
            for (int ni = 0; ni < 4; ++ni) {
                int col = colBase + wn + ni * 16 + l15;
                if (col >= Ncs) continue;
                float v = acc[mi][ni][r];
                if (bias) v += bias[col];
                stf(&C[(size_t)row * Ncs + col], v);
            }
        }
    }
}

// ---------------------------------------------------------------------------
// weight prep kernels
// ---------------------------------------------------------------------------
// fp32 W[512,512] x2 -> bf16 Wt[1024,512] (transposed, stacked), grid.z=2
__global__ void convert_transpose2(const float* __restrict__ W0,
                                   const float* __restrict__ W1,
                                   bf16* __restrict__ Wt) {
    __shared__ float tile[32][33];
    const float* W = blockIdx.z ? W1 : W0;
    bf16* dst = Wt + (size_t)blockIdx.z * D * D;
    int bn = blockIdx.x * 32, bk = blockIdx.y * 32;
    int tx = threadIdx.x & 31, ty = threadIdx.x >> 5;  // 32x8
    #pragma unroll
    for (int i = 0; i < 32; i += 8)
        tile[ty + i][tx] = W[(size_t)(bk + ty + i) * D + bn + tx];
    __syncthreads();
    #pragma unroll
    for (int i = 0; i < 32; i += 8)
        dst[(size_t)(bn + ty + i) * D + bk + tx] = __float2bfloat16(tile[tx][ty + i]);
}

__global__ void pad_convert_x(const float* __restrict__ x, bf16* __restrict__ Xp) {
    int idx = blockIdx.x * blockDim.x + threadIdx.x;
    if (idx >= NN * F0P) return;
    int n = idx >> 6, t = idx & 63;
    float v = (t < F0) ? x[n * F0 + t] : 0.f;
    Xp[idx] = __float2bfloat16(v);
}

// W1{l,r}[55,512] fp32 -> W1T[1024,64] bf16 (zero pad K), grid.y=2
__global__ void conv_transpose_w1(const float* __restrict__ Wl,
                                  const float* __restrict__ Wr,
                                  bf16* __restrict__ Wt) {
    const float* W = blockIdx.y ? Wr : Wl;
    bf16* dst = Wt + (size_t)blockIdx.y * D * F0P;
    int n = blockIdx.x;           // 512
    int k = threadIdx.x;          // 64
    float v = (k < F0) ? W[(size_t)k * D + n] : 0.f;
    dst[n * F0P + k] = __float2bfloat16(v);
}

__global__ void conv_transpose_wc(const float* __restrict__ W, bf16* __restrict__ Wt) {
    int n = blockIdx.x;           // 128
    for (int k = threadIdx.x; k < D; k += blockDim.x) {
        float v = (n < OUTC) ? W[(size_t)k * OUTC + n] : 0.f;
        Wt[(size_t)n * D + k] = __float2bfloat16(v);
    }
}

// ---------------------------------------------------------------------------
__global__ void zero_ints(int* __restrict__ p, int n) {
    int i = blockIdx.x * blockDim.x + threadIdx.x;
    if (i < n) p[i] = 0;
}

// ---------------------------------------------------------------------------
// CSR build by destination; srcPos[pos] = source node of CSR slot pos
// ---------------------------------------------------------------------------
__global__ void count_dst(const int* __restrict__ dstIdx, int* __restrict__ cnt) {
    int e = blockIdx.x * blockDim.x + threadIdx.x;
    if (e >= EP) return;
    int dst = (e < EE) ? dstIdx[e] : (e - EE);
    atomicAdd(&cnt[dst], 1);
}

__global__ void scan_blocks(const int* __restrict__ cnt, int* __restrict__ off,
                            int* __restrict__ bsum) {
    __shared__ int sh[1024];
    int i = blockIdx.x * 1024 + threadIdx.x;
    int v = (i < NN) ? cnt[i] : 0;
    sh[threadIdx.x] = v;
    __syncthreads();
    #pragma unroll
    for (int d = 1; d < 1024; d <<= 1) {
        int t = (threadIdx.x >= d) ? sh[threadIdx.x - d] : 0;
        __syncthreads();
        sh[threadIdx.x] += t;
        __syncthreads();
    }
    if (i < NN) off[i] = sh[threadIdx.x] - v;   // local exclusive
    if (threadIdx.x == 1023) bsum[blockIdx.x] = sh[1023];
}

__global__ void scan_bsums(int* __restrict__ bsum, int* __restrict__ bbase,
                           int* __restrict__ off, int nb) {
    int lane = threadIdx.x;  // single wave of 64
    int orig = (lane < nb) ? bsum[lane] : 0;
    int v = orig;
    #pragma unroll
    for (int d = 1; d < 64; d <<= 1) {
        int t = __shfl_up(v, d);
        if (lane >= d) v += t;
    }
    if (lane < nb) bbase[lane] = v - orig;      // exclusive base per block
    if (lane == 63) off[NN] = v;                // grand total
}

__global__ void add_base(int* __restrict__ off, const int* __restrict__ bbase) {
    int i = blockIdx.x * 1024 + threadIdx.x;
    if (blockIdx.x == 0 || i >= NN) return;
    off[i] += bbase[blockIdx.x];
}

__global__ void fill_srcpos(const int* __restrict__ srcIdx, const int* __restrict__ dstIdx,
                            const int* __restrict__ off, int* __restrict__ cnt,
                            int* __restrict__ srcPos) {
    int e = blockIdx.x * blockDim.x + threadIdx.x;
    if (e >= EP) return;
    int dst = (e < EE) ? dstIdx[e] : (e - EE);
    int src = (e < EE) ? srcIdx[e] : (e - EE);
    int pos = off[dst] + atomicAdd(&cnt[dst], 1);
    srcPos[pos] = src;
}

// ---------------------------------------------------------------------------
// Degree-binned node ordering — block-aggregated counting sort (r9, fixed).
// LDS-local histogram/offsets per 256-thr block, then <=64 global atomics
// per block. perm is a bijection; order within a bin nondeterministic —
// perf-only, per-node outputs exact.
// ---------------------------------------------------------------------------
__global__ void hist_deg(const int* __restrict__ cnt, int* __restrict__ hist) {
    __shared__ int lh[64];
    if (threadIdx.x < 64) lh[threadIdx.x] = 0;
    __syncthreads();
    int v = blockIdx.x * blockDim.x + threadIdx.x;
    if (v < NN) atomicAdd(&lh[min(cnt[v], 63)], 1);
    __syncthreads();
    if (threadIdx.x < 64 && lh[threadIdx.x])
        atomicAdd(&hist[threadIdx.x], lh[threadIdx.x]);
}

__global__ void scan_hist(int* __restrict__ hist) {   // 1 wave of 64
    int lane = threadIdx.x;
    int orig = hist[lane];
    int v = orig;
    #pragma unroll
    for (int d = 1; d < 64; d <<= 1) {
        int t = __shfl_up(v, d);
        if (lane >= d) v += t;
    }
    hist[lane] = v - orig;          // exclusive base; mutated by scatter next
}

__global__ void scatter_perm(const int* __restrict__ cnt, int* __restrict__ hist,
                             int* __restrict__ perm) {
    __shared__ int lh[64];   // local per-bin counts -> local offsets
    __shared__ int gb[64];   // global base reserved for this block
    if (threadIdx.x < 64) lh[threadIdx.x] = 0;
    __syncthreads();
    int v = blockIdx.x * blockDim.x + threadIdx.x;
    int bin = 0, loc = 0;
    if (v < NN) {
        bin = min(cnt[v], 63);
        loc = atomicAdd(&lh[bin], 1);        // LDS atomic: cheap
    }
    __syncthreads();
    if (threadIdx.x < 64) {
        int c = lh[threadIdx.x];
        gb[threadIdx.x] = c ? atomicAdd(&hist[threadIdx.x], c) : 0;
    }
    __syncthreads();
    if (v < NN) perm[gb[bin] + loc] = v;
}

// ---------------------------------------------------------------------------
// FUSED GATv2 edge phase — round-20: DECOUPLED index/data prefetch streams.
// r9 equilibrium: 82 µs, VALU 67%, HBM-side 41%, Occ 71% — nothing
// saturated. Diagnosis: `XLR + srcPos[i+2]*D2` chains TWO dependent loads
// issued at one point -> effective data-prefetch depth ~1. Little's law:
// ~1.5 outstanding 256B/wave x 23 waves/CU x 256 CU at ~700ns ~ 3.3 TB/s
// = measured. Fix: prefetch srcPos FOUR ahead (j2,j3 resident ints), data
// TWO ahead using already-resident indices -> pipeline depth 4, ~2x
// outstanding. Index clamp (deg>=1 via self-loops) makes loads
// unconditional (branches removed); clamped tail re-loads are L1-hits.
// Processing order & math identical to r9 -> bitwise-same output.
// Wave = 1 head x 4 nodes (16 lanes/node, 8 ch/lane); head h pinned to
// XCD pair {2h,2h+1} via h=(bid&7)>>1. v = perm[rank].
// ---------------------------------------------------------------------------
__global__ __launch_bounds__(256) void gat_edge_head(
    const bf16* __restrict__ XLR, const float* __restrict__ att,
    const int* __restrict__ off, const int* __restrict__ srcPos,
    const int* __restrict__ perm, const float* __restrict__ bias,
    bf16* __restrict__ Hout)
{
    int bid = blockIdx.x;
    int h   = (bid & 7) >> 1;                    // head 0..3 -> XCD pair
    int nb  = ((bid >> 3) << 1) + (bid & 1);     // node-block per head
    if (nb >= NN / 16) return;                   // 3125 blocks/head (uniform)
    int lane = threadIdx.x & 63;
    int grp  = lane >> 4;                        // node slot 0..3 in wave
    int l16  = lane & 15;                        // 16 lanes per node
    int rank = nb * 16 + (int)(threadIdx.x >> 6) * 4 + grp;   // < 50000
    int v = perm[rank];                          // degree-binned order
    const int hoff = h * 128 + l16 * 8;          // this lane's 8 channels
    const bf16* __restrict__ XLRh = XLR + hoff;  // hoisted gather base

    uint4 ru = *(const uint4*)(XLRh + (size_t)v * D2 + D);
    v2f xr[4]; unpack8v(ru, xr);
    const float4* a4 = (const float4*)(att + hoff);
    float4 aa = a4[0], ab = a4[1];
    v2f at[4] = {v2f{aa.x, aa.y}, v2f{aa.z, aa.w},
                 v2f{ab.x, ab.y}, v2f{ab.z, ab.w}};
    const v2f k02 = {0.2f, 0.2f};

    int s0 = off[v], s1 = off[v + 1];            // deg >= 1 (self-loop)
    const int e1 = s1 - 1;
    float den = 0.f;
    v2f acc[4] = {v2f{0.f, 0.f}, v2f{0.f, 0.f}, v2f{0.f, 0.f}, v2f{0.f, 0.f}};

    // ---- decoupled prefetch: indices 4 ahead, data 2 ahead ----
    int t1 = s0 + 1 < e1 ? s0 + 1 : e1;
    int t2 = s0 + 2 < e1 ? s0 + 2 : e1;
    int t3 = s0 + 3 < e1 ? s0 + 3 : e1;
    int j0 = srcPos[s0];
    int j1 = srcPos[t1];
    int j2 = srcPos[t2];                         // resident index, i+2
    int j3 = srcPos[t3];                         // resident index, i+3
    uint4 lb0 = *(const uint4*)(XLRh + (size_t)j0 * D2);
    uint4 lb1 = *(const uint4*)(XLRh + (size_t)j1 * D2);

    for (int i = s0; i < s1; ++i) {
        uint4 cur = lb0;
        lb0 = lb1;
        lb1 = *(const uint4*)(XLRh + (size_t)j2 * D2);   // index already here
        j2 = j3;
        int nx = i + 4; nx = nx < e1 ? nx : e1;
        j3 = srcPos[nx];                                 // consumed 2 iters on

        v2f xl[4]; unpack8v(cur, xl);
        v2f s2 = {0.f, 0.f};
        #pragma unroll
        for (int j = 0; j < 4; ++j) {
            v2f t = xl[j] + xr[j];        // v_pk_add_f32
            v2f u = t * k02;              // v_pk_mul_f32
            t.x = fmaxf(t.x, u.x);        // leaky relu (valid both signs)
            t.y = fmaxf(t.y, u.y);
            s2 = t * at[j] + s2;          // v_pk_fma_f32
        }
        float s = s2.x + s2.y;
        s += __shfl_xor(s, 1);
        s += __shfl_xor(s, 2);
        s += __shfl_xor(s, 4);
        s += __shfl_xor(s, 8);               // 16-lane group holds head logit
        s = fminf(fmaxf(s, -60.f), 60.f);    // shift-free softmax, clamped
        float p = __expf(s);
        den += p;
        v2f pv = {p, p};
        #pragma unroll
        for (int j = 0; j < 4; ++j) acc[j] = xl[j] * pv + acc[j];   // pk fma
    }
    float r = 1.f / den;
    v2f rv = {r, r};

    const float4* b4 = (const float4*)(bias + hoff);
    float4 ba = b4[0], bb = b4[1];
    v2f bi[4] = {v2f{ba.x, ba.y}, v2f{ba.z, ba.w},
                 v2f{bb.x, bb.y}, v2f{bb.z, bb.w}};
    uint4 ou;
    unsigned* ow = (unsigned*)&ou;
    #pragma unroll
    for (int j = 0; j < 4; ++j) {
        v2f o = acc[j] * rv + bi[j];                 // v_pk_fma_f32
        float o0 = o.x > 0.f ? o.x : (__expf(o.x) - 1.f);   // ELU
        float o1 = o.y > 0.f ? o.y : (__expf(o.y) - 1.f);
        __hip_bfloat162 hh{__float2bfloat16(o0), __float2bfloat16(o1)};
        ow[j] = *(unsigned*)&hh;
    }
    *(uint4*)(Hout + (size_t)v * D + hoff) = ou;
}

// ---------------------------------------------------------------------------
extern "C" void kernel_launch(void* const* d_in, const int* in_sizes, int n_in,
                              void* d_out, int out_size, void* d_ws, size_t ws_size,
                              hipStream_t stream) {
    const float* x    = (const float*)d_in[0];
    const int*   ei   = (const int*)d_in[1];
    const float* W1l  = (const float*)d_in[2];
    const float* W1r  = (const float*)d_in[3];
    const float* att1 = (const float*)d_in[4];
    const float* b1   = (const float*)d_in[5];
    const float* W2l  = (const float*)d_in[6];
    const float* W2r  = (const float*)d_in[7];
    const float* att2 = (const float*)d_in[8];
    const float* b2   = (const float*)d_in[9];
    const float* Wc   = (const float*)d_in[10];
    const float* bc   = (const float*)d_in[11];
    float* out = (float*)d_out;

    const int* srcIdx = ei;
    const int* dstIdx = ei + EE;

    constexpr int NB = (NN + 1023) / 1024;   // 49 scan blocks

    // workspace carve — total ≈ 166 MB
    bf16* XLR  = (bf16*)d_ws;                    // NN*D2   (XL || XR)
    bf16* Hb   = XLR + (size_t)NN * D2;          // NN*D
    bf16* Xpad = Hb + (size_t)NN * D;            // NN*F0P
    bf16* W2T  = Xpad + (size_t)NN * F0P;        // 1024*D   (W2lT || W2rT rows)
    bf16* W1T  = W2T + (size_t)D2 * D;           // 1024*F0P
    bf16* WcT  = W1T + (size_t)D2 * F0P;         // 128*D
    int* cnt   = (int*)(WcT + (size_t)128 * D);  // NN
    int* cnt2  = cnt + NN;                       // NN
    int* hist  = cnt2 + NN;                      // 64 (zeroed with cnt/cnt2)
    int* off   = hist + 64;                      // NN+1
    int* srcPos= off + (NN + 1);                 // EP
    int* bsum  = srcPos + EP;                    // NB
    int* bbase = bsum + NB;                      // NB
    int* perm  = bbase + NB;                     // NN

    // ---- one-time per call: CSR build + weight prep + degree binning ----
    zero_ints<<<(2 * NN + 64 + 255) / 256, 256, 0, stream>>>(cnt, 2 * NN + 64);
    count_dst<<<(EP + 255) / 256, 256, 0, stream>>>(dstIdx, cnt);
    scan_blocks<<<NB, 1024, 0, stream>>>(cnt, off, bsum);
    scan_bsums<<<1, 64, 0, stream>>>(bsum, bbase, off, NB);
    add_base<<<NB, 1024, 0, stream>>>(off, bbase);
    fill_srcpos<<<(EP + 255) / 256, 256, 0, stream>>>(srcIdx, dstIdx, off, cnt2, srcPos);
    hist_deg<<<(NN + 255) / 256, 256, 0, stream>>>(cnt, hist);
    scan_hist<<<1, 64, 0, stream>>>(hist);
    scatter_perm<<<(NN + 255) / 256, 256, 0, stream>>>(cnt, hist, perm);

    dim3 ctGrid(D / 32, D / 32, 2);
    convert_transpose2<<<ctGrid, 256, 0, stream>>>(W2l, W2r, W2T);
    dim3 w1Grid(D, 2);
    conv_transpose_w1<<<w1Grid, F0P, 0, stream>>>(W1l, W1r, W1T);
    conv_transpose_wc<<<128, 256, 0, stream>>>(Wc, WcT);
    pad_convert_x<<<(NN * F0P + 255) / 256, 256, 0, stream>>>(x, Xpad);

    // BM=256 row-panels: pad grid.y to a multiple of 8 for the XCD swizzle
    int panels = (NN + 255) / 256;                       // 196
    int gy = (panels + 7) / 8 * 8;                       // 200
    dim3 gemmGrid(D2 / 128, gy);                         // 8 x 200
    // head-split edge kernel: 4 heads x 3125 node-blocks = 12500, pad to 12504
    int headBlocks = 12504;

    // ---- layer 1 (Xpad bf16, K=64): one GEMM produces XL||XR ----
    gemm_dp<bf16, 2><<<gemmGrid, 512, 0, stream>>>(Xpad, W1T, XLR, nullptr, NN, D2);
    gat_edge_head<<<headBlocks, 256, 0, stream>>>(XLR, att1, off, srcPos, perm, b1, Hb);

    // ---- layers 2 & 3 (bf16 Hb, K=512; conv2 applied twice) ----
    for (int rep = 0; rep < 2; ++rep) {
        gemm_dp<bf16, 16><<<gemmGrid, 512, 0, stream>>>(Hb, W2T, XLR, nullptr, NN, D2);
        gat_edge_head<<<headBlocks, 256, 0, stream>>>(XLR, att2, off, srcPos, perm, b2, Hb);
    }

    // ---- classifier: C[NN,49] fp32 = Hb @ Wc + bc (N padded to 128) ----
    dim3 gridc(1, panels);
    gemm_dp<float, 16><<<gridc, 512, 0, stream>>>(Hb, WcT, out, bc, NN, OUTC);
}

// Round 11
// 564.633 us; speedup vs baseline: 1.0522x; 1.0522x over previous
//
#include <hip/hip_runtime.h>
#include <hip/hip_bf16.h>

// Problem constants (from reference setup_inputs)
constexpr int NN   = 50000;   // nodes
constexpr int EE   = 400000;  // edges (before self loops)
constexpr int EP   = 450000;  // edges + self loops
constexpr int D    = 512;     // HEADS*CH
constexpr int D2   = 1024;    // XL||XR fused row stride
constexpr int F0   = 55;      // input feature dim
constexpr int F0P  = 64;      // padded to MFMA K granularity
constexpr int OUTC = 49;      // classifier out dim

typedef __hip_bfloat16 bf16;

using frag_ab  = __attribute__((ext_vector_type(8))) short;   // 8 bf16 (4 VGPRs)
using frag_cd4 = __attribute__((ext_vector_type(4))) float;   // 4 fp32 (16x16 acc)

__device__ inline void stf(float* p, float v) { *p = v; }
__device__ inline void stf(bf16* p, float v)  { *p = __float2bfloat16(v); }

// unpack 8 bf16 (packed in a uint4) to 8 floats
__device__ inline void unpack8(uint4 u, float* f) {
    unsigned w[4] = {u.x, u.y, u.z, u.w};
    #pragma unroll
    for (int j = 0; j < 4; ++j) {
        __hip_bfloat162 h = *(__hip_bfloat162*)&w[j];
        float2 t = __bfloat1622float2(h);
        f[2 * j] = t.x; f[2 * j + 1] = t.y;
    }
}

// ---------------------------------------------------------------------------
// SESSION-BEST CONFIGURATION (r3 = 567.07 µs, reverted after r4-r10 A/Bs).
// Evidence ledger:
//   GEMM: BK=32 3-slot ring, 2 blocks/CU, counted vmcnt(3), one barrier/step
//     = best of 4 structures tried (drain-every-step 103 µs; graft-dbuf 105;
//     BK=64 8-phase 92; THIS ~72-75/dispatch). T2 swizzle verified
//     (conflicts 1.9e7 -> 0).
//   Edge: whole-row scalar, 4 nodes/256-thr block, depth-2 chained prefetch
//     = 80.4 µs, the service equilibrium. Five variants (pk, 2-edge ILP,
//     head-split, degree-binning, depth-4 decoupled prefetch) all converge
//     to 80-90 µs at ~3.3-3.7 TB/s random-gather service — fabric-side
//     ceiling; bytes/VALU/MLP levers all null or negative. Degree-sort
//     dropped (zero edge gain, prep overhead).
// ---------------------------------------------------------------------------
template <typename TC, int NS>
__global__ __launch_bounds__(512, 4) void gemm_dp(
    const bf16* __restrict__ A,   // [M,K]
    const bf16* __restrict__ Bt,  // [>=gridx*128 rows, K]
    TC* __restrict__ C,           // [M, Ncs]
    const float* __restrict__ bias,
    int M, int Ncs)
{
    constexpr int K  = NS * 32;
    constexpr int BM = 256, BN = 128, BK = 32;
    __shared__ __align__(16) bf16 As[3][BM * BK];   // 16 KB / slot
    __shared__ __align__(16) bf16 Bs[3][BN * BK];   //  8 KB / slot

    int bx = blockIdx.x, by = blockIdx.y;
    if (gridDim.x == 8) {
        int bid = by * 8 + bx;
        bx = (bid >> 3) & 7;
        by = (bid & 7) + ((bid >> 6) << 3);
    }
    if (by * BM >= M) return;   // uniform across block

    const int tid = threadIdx.x;
    const int w   = tid >> 6;       // wave 0..7
    const int l   = tid & 63;
    const int rowBase = by * BM;
    const int colBase = bx * BN;

    // ---- staging source pointers (inverse-swizzled global chunks) ----
    const bf16* gA[2];
    #pragma unroll
    for (int j = 0; j < 2; ++j) {
        int f = j * 512 + tid;
        int row = f >> 2, c = (f & 3) ^ ((row >> 1) & 3);
        int ar = rowBase + row; if (ar >= M) ar = M - 1;  // clamp, never stored
        gA[j] = A + (size_t)ar * K + c * 8;
    }
    const bf16* gB;
    {
        int f = tid;
        int row = f >> 2, c = (f & 3) ^ ((row >> 1) & 3);
        gB = Bt + (size_t)(colBase + row) * K + c * 8;    // Bt rows padded
    }

    // ---- fragment read offsets (swizzled), element units ----
    const int l15 = l & 15, l4 = l >> 4;    // l4 = k-chunk 0..3
    const int wm = (w >> 1) * 64;   // wave M-block (4 x 64 rows)
    const int wn = (w & 1) * 64;    // wave N-block (2 x 64 cols)
    int aoff[4], boff[4];
    #pragma unroll
    for (int i = 0; i < 4; ++i) {
        int ra = wm + i * 16 + l15;
        int rb = wn + i * 16 + l15;
        aoff[i] = ra * BK + ((l4 ^ ((ra >> 1) & 3)) * 8);
        boff[i] = rb * BK + ((l4 ^ ((rb >> 1) & 3)) * 8);
    }

    frag_cd4 acc[4][4] = {};

    auto stage = [&](int s) {
        int slot = s % 3;
        __builtin_amdgcn_global_load_lds(
            (const __attribute__((address_space(1))) void*)(gA[0] + s * BK),
            (__attribute__((address_space(3))) void*)(&As[slot][(w * 64) * 8]),
            16, 0, 0);
        __builtin_amdgcn_global_load_lds(
            (const __attribute__((address_space(1))) void*)(gA[1] + s * BK),
            (__attribute__((address_space(3))) void*)(&As[slot][(512 + w * 64) * 8]),
            16, 0, 0);
        __builtin_amdgcn_global_load_lds(
            (const __attribute__((address_space(1))) void*)(gB + s * BK),
            (__attribute__((address_space(3))) void*)(&Bs[slot][(w * 64) * 8]),
            16, 0, 0);
    };

    stage(0);
    if (NS > 1) stage(1);

    #pragma unroll
    for (int s = 0; s < NS; ++s) {
        if (s + 1 < NS) asm volatile("s_waitcnt vmcnt(3)" ::: "memory");
        else            asm volatile("s_waitcnt vmcnt(0)" ::: "memory");
        __builtin_amdgcn_s_barrier();
        asm volatile("" ::: "memory");

        if (s + 2 < NS) stage(s + 2);   // overwrites slot(s-1): WAR-safe

        const bf16* Ab = As[s % 3];
        const bf16* Bb = Bs[s % 3];
        frag_ab a[4], b[4];
        #pragma unroll
        for (int i = 0; i < 4; ++i) a[i] = *(const frag_ab*)&Ab[aoff[i]];
        #pragma unroll
        for (int n = 0; n < 4; ++n) b[n] = *(const frag_ab*)&Bb[boff[n]];

        __builtin_amdgcn_s_setprio(1);
        #pragma unroll
        for (int i = 0; i < 4; ++i)
            #pragma unroll
            for (int n = 0; n < 4; ++n)
                acc[i][n] = __builtin_amdgcn_mfma_f32_16x16x32_bf16(
                    a[i], b[n], acc[i][n], 0, 0, 0);
        __builtin_amdgcn_s_setprio(0);
    }

    // ---- epilogue: 16x16 C/D layout col=lane&15, row=(lane>>4)*4+reg ----
    #pragma unroll
    for (int mi = 0; mi < 4; ++mi) {
        #pragma unroll
        for (int r = 0; r < 4; ++r) {
            int row = rowBase + wm + mi * 16 + l4 * 4 + r;
            if (row >= M) continue;
            #pragma unroll
            for (int ni = 0; ni < 4; ++ni) {
                int col = colBase + wn + ni * 16 + l15;
                if (col >= Ncs) continue;
                float v = acc[mi][ni][r];
                if (bias) v += bias[col];
                stf(&C[(size_t)row * Ncs + col], v);
            }
        }
    }
}

// ---------------------------------------------------------------------------
// weight prep kernels
// ---------------------------------------------------------------------------
// fp32 W[512,512] x2 -> bf16 Wt[1024,512] (transposed, stacked), grid.z=2
__global__ void convert_transpose2(const float* __restrict__ W0,
                                   const float* __restrict__ W1,
                                   bf16* __restrict__ Wt) {
    __shared__ float tile[32][33];
    const float* W = blockIdx.z ? W1 : W0;
    bf16* dst = Wt + (size_t)blockIdx.z * D * D;
    int bn = blockIdx.x * 32, bk = blockIdx.y * 32;
    int tx = threadIdx.x & 31, ty = threadIdx.x >> 5;  // 32x8
    #pragma unroll
    for (int i = 0; i < 32; i += 8)
        tile[ty + i][tx] = W[(size_t)(bk + ty + i) * D + bn + tx];
    __syncthreads();
    #pragma unroll
    for (int i = 0; i < 32; i += 8)
        dst[(size_t)(bn + ty + i) * D + bk + tx] = __float2bfloat16(tile[tx][ty + i]);
}

__global__ void pad_convert_x(const float* __restrict__ x, bf16* __restrict__ Xp) {
    int idx = blockIdx.x * blockDim.x + threadIdx.x;
    if (idx >= NN * F0P) return;
    int n = idx >> 6, t = idx & 63;
    float v = (t < F0) ? x[n * F0 + t] : 0.f;
    Xp[idx] = __float2bfloat16(v);
}

// W1{l,r}[55,512] fp32 -> W1T[1024,64] bf16 (zero pad K), grid.y=2
__global__ void conv_transpose_w1(const float* __restrict__ Wl,
                                  const float* __restrict__ Wr,
                                  bf16* __restrict__ Wt) {
    const float* W = blockIdx.y ? Wr : Wl;
    bf16* dst = Wt + (size_t)blockIdx.y * D * F0P;
    int n = blockIdx.x;           // 512
    int k = threadIdx.x;          // 64
    float v = (k < F0) ? W[(size_t)k * D + n] : 0.f;
    dst[n * F0P + k] = __float2bfloat16(v);
}

__global__ void conv_transpose_wc(const float* __restrict__ W, bf16* __restrict__ Wt) {
    int n = blockIdx.x;           // 128
    for (int k = threadIdx.x; k < D; k += blockDim.x) {
        float v = (n < OUTC) ? W[(size_t)k * OUTC + n] : 0.f;
        Wt[(size_t)n * D + k] = __float2bfloat16(v);
    }
}

// ---------------------------------------------------------------------------
__global__ void zero_ints(int* __restrict__ p, int n) {
    int i = blockIdx.x * blockDim.x + threadIdx.x;
    if (i < n) p[i] = 0;
}

// ---------------------------------------------------------------------------
// CSR build by destination; srcPos[pos] = source node of CSR slot pos
// ---------------------------------------------------------------------------
__global__ void count_dst(const int* __restrict__ dstIdx, int* __restrict__ cnt) {
    int e = blockIdx.x * blockDim.x + threadIdx.x;
    if (e >= EP) return;
    int dst = (e < EE) ? dstIdx[e] : (e - EE);
    atomicAdd(&cnt[dst], 1);
}

__global__ void scan_blocks(const int* __restrict__ cnt, int* __restrict__ off,
                            int* __restrict__ bsum) {
    __shared__ int sh[1024];
    int i = blockIdx.x * 1024 + threadIdx.x;
    int v = (i < NN) ? cnt[i] : 0;
    sh[threadIdx.x] = v;
    __syncthreads();
    #pragma unroll
    for (int d = 1; d < 1024; d <<= 1) {
        int t = (threadIdx.x >= d) ? sh[threadIdx.x - d] : 0;
        __syncthreads();
        sh[threadIdx.x] += t;
        __syncthreads();
    }
    if (i < NN) off[i] = sh[threadIdx.x] - v;   // local exclusive
    if (threadIdx.x == 1023) bsum[blockIdx.x] = sh[1023];
}

__global__ void scan_bsums(int* __restrict__ bsum, int* __restrict__ bbase,
                           int* __restrict__ off, int nb) {
    int lane = threadIdx.x;  // single wave of 64
    int orig = (lane < nb) ? bsum[lane] : 0;
    int v = orig;
    #pragma unroll
    for (int d = 1; d < 64; d <<= 1) {
        int t = __shfl_up(v, d);
        if (lane >= d) v += t;
    }
    if (lane < nb) bbase[lane] = v - orig;      // exclusive base per block
    if (lane == 63) off[NN] = v;                // grand total
}

__global__ void add_base(int* __restrict__ off, const int* __restrict__ bbase) {
    int i = blockIdx.x * 1024 + threadIdx.x;
    if (blockIdx.x == 0 || i >= NN) return;
    off[i] += bbase[blockIdx.x];
}

__global__ void fill_srcpos(const int* __restrict__ srcIdx, const int* __restrict__ dstIdx,
                            const int* __restrict__ off, int* __restrict__ cnt,
                            int* __restrict__ srcPos) {
    int e = blockIdx.x * blockDim.x + threadIdx.x;
    if (e >= EP) return;
    int dst = (e < EE) ? dstIdx[e] : (e - EE);
    int src = (e < EE) ? srcIdx[e] : (e - EE);
    int pos = off[dst] + atomicAdd(&cnt[dst], 1);
    srcPos[pos] = src;
}

// ---------------------------------------------------------------------------
// FUSED per-node GATv2 edge phase — measured-best variant (80.4 µs).
// ONE wave per destination node, depth-2 prefetch, clamped-exp softmax.
// At the random-gather service equilibrium (~3.6 TB/s L2-miss path):
// r4-r10 proved VALU cuts (pk), ILP unrolls, head-split byte cuts, degree
// binning, and deeper prefetch are all null-to-negative here.
// Lane l owns channels [l*8, l*8+8); head = l>>4.
// XLR row layout: [XL(512) | XR(512)] bf16, stride D2. Output Hb + bias + ELU.
// ---------------------------------------------------------------------------
__global__ __launch_bounds__(256) void gat_edge_fused(
    const bf16* __restrict__ XLR, const float* __restrict__ att,
    const int* __restrict__ off, const int* __restrict__ srcPos,
    const float* __restrict__ bias, bf16* __restrict__ Hout)
{
    int v = blockIdx.x * 4 + (threadIdx.x >> 6);
    if (v >= NN) return;
    int lane = threadIdx.x & 63;

    uint4 ru = *(const uint4*)(XLR + (size_t)v * D2 + D + lane * 8);
    float xr[8]; unpack8(ru, xr);
    const float4* a4 = (const float4*)(att + lane * 8);
    float4 aa = a4[0], ab = a4[1];
    float at[8] = {aa.x, aa.y, aa.z, aa.w, ab.x, ab.y, ab.z, ab.w};

    int s0 = off[v], s1 = off[v + 1];
    float den = 0.f;
    float acc[8] = {};

    uint4 lb0 = {0, 0, 0, 0}, lb1 = {0, 0, 0, 0};
    if (s0 < s1)     lb0 = *(const uint4*)(XLR + (size_t)srcPos[s0] * D2 + lane * 8);
    if (s0 + 1 < s1) lb1 = *(const uint4*)(XLR + (size_t)srcPos[s0 + 1] * D2 + lane * 8);

    for (int i = s0; i < s1; ++i) {
        uint4 cur = lb0;
        lb0 = lb1;
        if (i + 2 < s1)
            lb1 = *(const uint4*)(XLR + (size_t)srcPos[i + 2] * D2 + lane * 8);

        float xl[8]; unpack8(cur, xl);
        float sa = 0.f, sb = 0.f;
        #pragma unroll
        for (int j = 0; j < 4; ++j) {
            float t = xl[j] + xr[j];
            t = fmaxf(t, 0.2f * t);          // leaky relu (valid both signs)
            sa = fmaf(t, at[j], sa);
        }
        #pragma unroll
        for (int j = 4; j < 8; ++j) {
            float t = xl[j] + xr[j];
            t = fmaxf(t, 0.2f * t);
            sb = fmaf(t, at[j], sb);
        }
        float s = sa + sb;
        s += __shfl_xor(s, 1);
        s += __shfl_xor(s, 2);
        s += __shfl_xor(s, 4);
        s += __shfl_xor(s, 8);               // 16 lanes of head hold logit
        s = fminf(fmaxf(s, -60.f), 60.f);    // shift-free softmax, clamped
        float p = __expf(s);
        den += p;
        #pragma unroll
        for (int j = 0; j < 8; ++j) acc[j] = fmaf(p, xl[j], acc[j]);
    }
    float r = 1.f / den;

    const float4* b4 = (const float4*)(bias + lane * 8);
    float4 ba = b4[0], bb = b4[1];
    float bi[8] = {ba.x, ba.y, ba.z, ba.w, bb.x, bb.y, bb.z, bb.w};
    uint4 ou;
    unsigned* ow = (unsigned*)&ou;
    #pragma unroll
    for (int j = 0; j < 4; ++j) {
        float o0 = acc[2 * j] * r + bi[2 * j];
        float o1 = acc[2 * j + 1] * r + bi[2 * j + 1];
        o0 = o0 > 0.f ? o0 : (__expf(o0) - 1.f);   // ELU
        o1 = o1 > 0.f ? o1 : (__expf(o1) - 1.f);
        __hip_bfloat162 h{__float2bfloat16(o0), __float2bfloat16(o1)};
        ow[j] = *(unsigned*)&h;
    }
    *(uint4*)(Hout + (size_t)v * D + lane * 8) = ou;
}

// ---------------------------------------------------------------------------
extern "C" void kernel_launch(void* const* d_in, const int* in_sizes, int n_in,
                              void* d_out, int out_size, void* d_ws, size_t ws_size,
                              hipStream_t stream) {
    const float* x    = (const float*)d_in[0];
    const int*   ei   = (const int*)d_in[1];
    const float* W1l  = (const float*)d_in[2];
    const float* W1r  = (const float*)d_in[3];
    const float* att1 = (const float*)d_in[4];
    const float* b1   = (const float*)d_in[5];
    const float* W2l  = (const float*)d_in[6];
    const float* W2r  = (const float*)d_in[7];
    const float* att2 = (const float*)d_in[8];
    const float* b2   = (const float*)d_in[9];
    const float* Wc   = (const float*)d_in[10];
    const float* bc   = (const float*)d_in[11];
    float* out = (float*)d_out;

    const int* srcIdx = ei;
    const int* dstIdx = ei + EE;

    constexpr int NB = (NN + 1023) / 1024;   // 49 scan blocks

    // workspace carve — total ≈ 166 MB
    bf16* XLR  = (bf16*)d_ws;                    // NN*D2   (XL || XR)
    bf16* Hb   = XLR + (size_t)NN * D2;          // NN*D
    bf16* Xpad = Hb + (size_t)NN * D;            // NN*F0P
    bf16* W2T  = Xpad + (size_t)NN * F0P;        // 1024*D   (W2lT || W2rT rows)
    bf16* W1T  = W2T + (size_t)D2 * D;           // 1024*F0P
    bf16* WcT  = W1T + (size_t)D2 * F0P;         // 128*D
    int* cnt   = (int*)(WcT + (size_t)128 * D);  // NN
    int* cnt2  = cnt + NN;                       // NN
    int* off   = cnt2 + NN;                      // NN+1
    int* srcPos= off + (NN + 1);                 // EP
    int* bsum  = srcPos + EP;                    // NB
    int* bbase = bsum + NB;                      // NB

    // ---- one-time per call: CSR build + weight prep ----
    zero_ints<<<(2 * NN + 255) / 256, 256, 0, stream>>>(cnt, 2 * NN);
    count_dst<<<(EP + 255) / 256, 256, 0, stream>>>(dstIdx, cnt);
    scan_blocks<<<NB, 1024, 0, stream>>>(cnt, off, bsum);
    scan_bsums<<<1, 64, 0, stream>>>(bsum, bbase, off, NB);
    add_base<<<NB, 1024, 0, stream>>>(off, bbase);
    fill_srcpos<<<(EP + 255) / 256, 256, 0, stream>>>(srcIdx, dstIdx, off, cnt2, srcPos);

    dim3 ctGrid(D / 32, D / 32, 2);
    convert_transpose2<<<ctGrid, 256, 0, stream>>>(W2l, W2r, W2T);
    dim3 w1Grid(D, 2);
    conv_transpose_w1<<<w1Grid, F0P, 0, stream>>>(W1l, W1r, W1T);
    conv_transpose_wc<<<128, 256, 0, stream>>>(Wc, WcT);
    pad_convert_x<<<(NN * F0P + 255) / 256, 256, 0, stream>>>(x, Xpad);

    // BM=256 row-panels: pad grid.y to a multiple of 8 for the XCD swizzle
    int panels = (NN + 255) / 256;                       // 196
    int gy = (panels + 7) / 8 * 8;                       // 200
    dim3 gemmGrid(D2 / 128, gy);                         // 8 x 200
    int nodeBlocks = (NN + 3) / 4;                       // 4 nodes / 256-thr block

    // ---- layer 1 (Xpad bf16, K=64): one GEMM produces XL||XR ----
    gemm_dp<bf16, 2><<<gemmGrid, 512, 0, stream>>>(Xpad, W1T, XLR, nullptr, NN, D2);
    gat_edge_fused<<<nodeBlocks, 256, 0, stream>>>(XLR, att1, off, srcPos, b1, Hb);

    // ---- layers 2 & 3 (bf16 Hb, K=512; conv2 applied twice) ----
    for (int rep = 0; rep < 2; ++rep) {
        gemm_dp<bf16, 16><<<gemmGrid, 512, 0, stream>>>(Hb, W2T, XLR, nullptr, NN, D2);
        gat_edge_fused<<<nodeBlocks, 256, 0, stream>>>(XLR, att2, off, srcPos, b2, Hb);
    }

    // ---- classifier: C[NN,49] fp32 = Hb @ Wc + bc (N padded to 128) ----
    dim3 gridc(1, panels);
    gemm_dp<float, 16><<<gridc, 512, 0, stream>>>(Hb, WcT, out, bc, NN, OUTC);
}